// Round 15
// baseline (238.167 us; speedup 1.0000x reference)
//
#include <hip/hip_runtime.h>
#include <hip/hip_fp16.h>

#define IN_CH 256
#define OUT_CH 8
#define LROW 264          // LDS row stride in bf16 elems: 256 + 8 pad

typedef float f32x4  __attribute__((ext_vector_type(4)));
typedef unsigned int u32x4 __attribute__((ext_vector_type(4)));
typedef short short8v __attribute__((ext_vector_type(8)));
typedef short short4v __attribute__((ext_vector_type(4)));

__device__ __forceinline__ short f2bf(float f) {   // f32 -> bf16 (RNE)
    unsigned u = __float_as_uint(f);
    u += 0x7FFFu + ((u >> 16) & 1u);
    return (short)(u >> 16);
}

__device__ __forceinline__ float2 h2f(unsigned w) {  // 2 packed f16 -> 2 f32
    __half2 h = *(__half2*)&w;
    return __half22float2(h);
}

// ---------------------------------------------------------------------------
// Projection v7 EXACT (27.1 us, probe-ladder measured): one wave per 16-row
// tile, ~2 tiles per wave via grid-stride (amortizes W-fragment build),
// mfma_f32_16x16x32_bf16 x8 over K=256, per-wave LDS slice, no barriers.
// ---------------------------------------------------------------------------
__global__ __launch_bounds__(256) void proj_kernel(
    const float* __restrict__ X,
    const float* __restrict__ W1,
    const float* __restrict__ W2,
    __half* __restrict__ P1h,        // [n][8] f16
    __half* __restrict__ P2h,
    int n, int ntiles, int nwaves)
{
    __shared__ short Xs[4][16][LROW];          // 33792 B per block

    const int wv   = threadIdx.x >> 6;
    const int lane = threadIdx.x & 63;
    const int gw   = (blockIdx.x * 256 + threadIdx.x) >> 6;

    const int o  = lane & 15;                  // output column this lane owns
    const int lk = lane >> 4;                  // k-group 0..3

    const float* wrow = (o < 8) ? (W1 + (size_t)o * IN_CH)
                                : (W2 + (size_t)(o - 8) * IN_CH);
    short8v bfr[8];
    #pragma unroll
    for (int kb = 0; kb < 8; ++kb) {
        float4 u = *(const float4*)(wrow + kb * 32 + lk * 8);
        float4 v = *(const float4*)(wrow + kb * 32 + lk * 8 + 4);
        short8v b;
        b[0] = f2bf(u.x); b[1] = f2bf(u.y); b[2] = f2bf(u.z); b[3] = f2bf(u.w);
        b[4] = f2bf(v.x); b[5] = f2bf(v.y); b[6] = f2bf(v.z); b[7] = f2bf(v.w);
        bfr[kb] = b;
    }

    for (int t = gw; t < ntiles; t += nwaves) {
        const int r0 = t * 16;

        #pragma unroll
        for (int i = 0; i < 16; ++i) {
            float4 x = make_float4(0.f, 0.f, 0.f, 0.f);
            if (r0 + i < n)
                x = *(const float4*)(X + (size_t)(r0 + i) * IN_CH + lane * 4);
            short4v s;
            s[0] = f2bf(x.x); s[1] = f2bf(x.y); s[2] = f2bf(x.z); s[3] = f2bf(x.w);
            *(short4v*)&Xs[wv][i][lane * 4] = s;
        }
        // same-wave LDS write->read: compiler inserts lgkmcnt waits

        f32x4 acc = {0.f, 0.f, 0.f, 0.f};
        #pragma unroll
        for (int kb = 0; kb < 8; ++kb) {
            short8v a = *(const short8v*)&Xs[wv][o][kb * 32 + lk * 8];
            acc = __builtin_amdgcn_mfma_f32_16x16x32_bf16(a, bfr[kb], acc, 0, 0, 0);
        }

        #pragma unroll
        for (int r = 0; r < 4; ++r) {
            const int row = r0 + lk * 4 + r;
            if (row < n) {
                __half h = __float2half(acc[r]);
                if (o < 8) P1h[(size_t)row * OUT_CH + o] = h;
                else       P2h[(size_t)row * OUT_CH + (o - 8)] = h;
            }
        }
    }
}

// ---------------------------------------------------------------------------
// Gather g8: EXACT g2 structure (1 edge/thread, proven best) with ONE change:
// the two random table reads use __builtin_nontemporal_load (single
// global_load_dwordx4 + nt) -> no L1 allocation, no 128-B line fill from L2.
// Tables stay L2-served (nothing else allocates: idx loads + stores also nt).
// ---------------------------------------------------------------------------
__global__ __launch_bounds__(256) void gather_kernel(
    const int* __restrict__ e0,
    const int* __restrict__ e1,
    const u32x4* __restrict__ T1,   // [n] x 8 halves (native vec for nt load)
    const u32x4* __restrict__ T2,
    f32x4* __restrict__ outv,       // [E*2] float4
    int E, int n)
{
    const int stride = gridDim.x * 256;
    const unsigned nmax = (unsigned)(n - 1);
    for (int e = blockIdx.x * 256 + threadIdx.x; e < E; e += stride) {
        unsigned i0 = (unsigned)__builtin_nontemporal_load(e0 + e);
        unsigned i1 = (unsigned)__builtin_nontemporal_load(e1 + e);
        i0 = i0 > nmax ? nmax : i0;
        i1 = i1 > nmax ? nmax : i1;

        u32x4 a = __builtin_nontemporal_load(T1 + i0);   // nt: no L1 fill
        u32x4 b = __builtin_nontemporal_load(T2 + i1);

        unsigned a0 = a[0], a1 = a[1], a2 = a[2], a3 = a[3];
        unsigned b0 = b[0], b1 = b[1], b2 = b[2], b3 = b[3];

        float2 s0 = h2f(a0), s1 = h2f(a1), s2 = h2f(a2), s3 = h2f(a3);
        float2 t0 = h2f(b0), t1 = h2f(b1), t2 = h2f(b2), t3 = h2f(b3);

        f32x4 r0 = { s0.x + t0.x, s0.y + t0.y, s1.x + t1.x, s1.y + t1.y };
        f32x4 r1 = { s2.x + t2.x, s2.y + t2.y, s3.x + t3.x, s3.y + t3.y };

        size_t oi = 2u * (size_t)e;
        __builtin_nontemporal_store(r0, outv + oi);
        __builtin_nontemporal_store(r1, outv + oi + 1);
    }
}

extern "C" void kernel_launch(void* const* d_in, const int* in_sizes, int n_in,
                              void* d_out, int out_size, void* d_ws, size_t ws_size,
                              hipStream_t stream) {
    const float* X    = (const float*)d_in[0];
    const int*   eidx = (const int*)d_in[1];
    const float* W1   = (const float*)d_in[2];
    const float* W2   = (const float*)d_in[3];

    const int n = in_sizes[0] / IN_CH;   // 100000
    const int E = in_sizes[1] / 2;       // 6400000

    __half* P1h = (__half*)d_ws;                    // [n][8] f16 = 1.6 MB
    __half* P2h = P1h + (size_t)n * OUT_CH;         // [n][8] f16 = 1.6 MB

    const int ntiles = (n + 15) / 16;               // 6250
    const int proj_blocks = 768;                    // 3072 waves, ~2 tiles each
    const int nwaves = proj_blocks * 4;
    proj_kernel<<<proj_blocks, 256, 0, stream>>>(
        X, W1, W2, P1h, P2h, n, ntiles, nwaves);

    const int gather_blocks = (E + 255) / 256;      // 25000, 1 edge/thread
    gather_kernel<<<gather_blocks, 256, 0, stream>>>(
        eidx, eidx + E, (const u32x4*)P1h, (const u32x4*)P2h,
        (f32x4*)d_out, E, n);
}

// Round 16
// 122.907 us; speedup vs baseline: 1.9378x; 1.9378x over previous
//
#include <hip/hip_runtime.h>
#include <hip/hip_fp16.h>

#define IN_CH 256
#define OUT_CH 8
#define LROW 264          // LDS row stride in bf16 elems: 256 + 8 pad

typedef float f32x4  __attribute__((ext_vector_type(4)));
typedef unsigned int u32x4 __attribute__((ext_vector_type(4)));
typedef short short8v __attribute__((ext_vector_type(8)));
typedef short short4v __attribute__((ext_vector_type(4)));

__device__ __forceinline__ short f2bf(float f) {   // f32 -> bf16 (RNE)
    unsigned u = __float_as_uint(f);
    u += 0x7FFFu + ((u >> 16) & 1u);
    return (short)(u >> 16);
}

__device__ __forceinline__ float2 h2f(unsigned w) {  // 2 packed f16 -> 2 f32
    __half2 h = *(__half2*)&w;
    return __half22float2(h);
}

// ---------------------------------------------------------------------------
// Projection v7 EXACT (27.1 us, probe-ladder measured): one wave per 16-row
// tile, ~2 tiles per wave via grid-stride (amortizes W-fragment build),
// mfma_f32_16x16x32_bf16 x8 over K=256, per-wave LDS slice, no barriers.
// ---------------------------------------------------------------------------
__global__ __launch_bounds__(256) void proj_kernel(
    const float* __restrict__ X,
    const float* __restrict__ W1,
    const float* __restrict__ W2,
    __half* __restrict__ P1h,        // [n][8] f16
    __half* __restrict__ P2h,
    int n, int ntiles, int nwaves)
{
    __shared__ short Xs[4][16][LROW];          // 33792 B per block

    const int wv   = threadIdx.x >> 6;
    const int lane = threadIdx.x & 63;
    const int gw   = (blockIdx.x * 256 + threadIdx.x) >> 6;

    const int o  = lane & 15;                  // output column this lane owns
    const int lk = lane >> 4;                  // k-group 0..3

    const float* wrow = (o < 8) ? (W1 + (size_t)o * IN_CH)
                                : (W2 + (size_t)(o - 8) * IN_CH);
    short8v bfr[8];
    #pragma unroll
    for (int kb = 0; kb < 8; ++kb) {
        float4 u = *(const float4*)(wrow + kb * 32 + lk * 8);
        float4 v = *(const float4*)(wrow + kb * 32 + lk * 8 + 4);
        short8v b;
        b[0] = f2bf(u.x); b[1] = f2bf(u.y); b[2] = f2bf(u.z); b[3] = f2bf(u.w);
        b[4] = f2bf(v.x); b[5] = f2bf(v.y); b[6] = f2bf(v.z); b[7] = f2bf(v.w);
        bfr[kb] = b;
    }

    for (int t = gw; t < ntiles; t += nwaves) {
        const int r0 = t * 16;

        #pragma unroll
        for (int i = 0; i < 16; ++i) {
            float4 x = make_float4(0.f, 0.f, 0.f, 0.f);
            if (r0 + i < n)
                x = *(const float4*)(X + (size_t)(r0 + i) * IN_CH + lane * 4);
            short4v s;
            s[0] = f2bf(x.x); s[1] = f2bf(x.y); s[2] = f2bf(x.z); s[3] = f2bf(x.w);
            *(short4v*)&Xs[wv][i][lane * 4] = s;
        }
        // same-wave LDS write->read: compiler inserts lgkmcnt waits

        f32x4 acc = {0.f, 0.f, 0.f, 0.f};
        #pragma unroll
        for (int kb = 0; kb < 8; ++kb) {
            short8v a = *(const short8v*)&Xs[wv][o][kb * 32 + lk * 8];
            acc = __builtin_amdgcn_mfma_f32_16x16x32_bf16(a, bfr[kb], acc, 0, 0, 0);
        }

        #pragma unroll
        for (int r = 0; r < 4; ++r) {
            const int row = r0 + lk * 4 + r;
            if (row < n) {
                __half h = __float2half(acc[r]);
                if (o < 8) P1h[(size_t)row * OUT_CH + o] = h;
                else       P2h[(size_t)row * OUT_CH + (o - 8)] = h;
            }
        }
    }
}

// ---------------------------------------------------------------------------
// Gather g9: EXACT g2 structure, ONE change: both table reads issued as
// global_load_dwordx4 with sc0 (agent scope: L1-bypass, L2-ALLOCATE, single
// 16-B request) in one asm block, shared vmcnt(0) -> MLP preserved.
// Distinguishes request-rate-bound (neutral) from L1-fill-bound (win).
// ---------------------------------------------------------------------------
__global__ __launch_bounds__(256) void gather_kernel(
    const int* __restrict__ e0,
    const int* __restrict__ e1,
    const u32x4* __restrict__ T1,   // [n] x 8 halves
    const u32x4* __restrict__ T2,
    f32x4* __restrict__ outv,       // [E*2] float4
    int E, int n)
{
    const int stride = gridDim.x * 256;
    const unsigned nmax = (unsigned)(n - 1);
    for (int e = blockIdx.x * 256 + threadIdx.x; e < E; e += stride) {
        unsigned i0 = (unsigned)__builtin_nontemporal_load(e0 + e);
        unsigned i1 = (unsigned)__builtin_nontemporal_load(e1 + e);
        i0 = i0 > nmax ? nmax : i0;
        i1 = i1 > nmax ? nmax : i1;

        const u32x4* pa = T1 + i0;
        const u32x4* pb = T2 + i1;
        u32x4 a, b;
        asm volatile(
            "global_load_dwordx4 %0, %2, off sc0\n\t"
            "global_load_dwordx4 %1, %3, off sc0\n\t"
            "s_waitcnt vmcnt(0)"
            : "=&v"(a), "=&v"(b)
            : "v"(pa), "v"(pb)
            : "memory");

        unsigned a0 = a[0], a1 = a[1], a2 = a[2], a3 = a[3];
        unsigned b0 = b[0], b1 = b[1], b2 = b[2], b3 = b[3];

        float2 s0 = h2f(a0), s1 = h2f(a1), s2 = h2f(a2), s3 = h2f(a3);
        float2 t0 = h2f(b0), t1 = h2f(b1), t2 = h2f(b2), t3 = h2f(b3);

        f32x4 r0 = { s0.x + t0.x, s0.y + t0.y, s1.x + t1.x, s1.y + t1.y };
        f32x4 r1 = { s2.x + t2.x, s2.y + t2.y, s3.x + t3.x, s3.y + t3.y };

        size_t oi = 2u * (size_t)e;
        __builtin_nontemporal_store(r0, outv + oi);
        __builtin_nontemporal_store(r1, outv + oi + 1);
    }
}

extern "C" void kernel_launch(void* const* d_in, const int* in_sizes, int n_in,
                              void* d_out, int out_size, void* d_ws, size_t ws_size,
                              hipStream_t stream) {
    const float* X    = (const float*)d_in[0];
    const int*   eidx = (const int*)d_in[1];
    const float* W1   = (const float*)d_in[2];
    const float* W2   = (const float*)d_in[3];

    const int n = in_sizes[0] / IN_CH;   // 100000
    const int E = in_sizes[1] / 2;       // 6400000

    __half* P1h = (__half*)d_ws;                    // [n][8] f16 = 1.6 MB
    __half* P2h = P1h + (size_t)n * OUT_CH;         // [n][8] f16 = 1.6 MB

    const int ntiles = (n + 15) / 16;               // 6250
    const int proj_blocks = 768;                    // 3072 waves, ~2 tiles each
    const int nwaves = proj_blocks * 4;
    proj_kernel<<<proj_blocks, 256, 0, stream>>>(
        X, W1, W2, P1h, P2h, n, ntiles, nwaves);

    const int gather_blocks = (E + 255) / 256;      // 25000, 1 edge/thread
    gather_kernel<<<gather_blocks, 256, 0, stream>>>(
        eidx, eidx + E, (const u32x4*)P1h, (const u32x4*)P2h,
        (f32x4*)d_out, E, n);
}